// Round 20
// baseline (653.883 us; speedup 1.0000x reference)
//
#include <hip/hip_runtime.h>
#include <hip/hip_bf16.h>

#define H 128
#define REGSZ 512      // nodes per region (power of 2)
#define PCHUNK 4096    // edges per partition block

typedef short short8 __attribute__((ext_vector_type(8)));
typedef float f32x4 __attribute__((ext_vector_type(4)));

__device__ __forceinline__ float bf2f(unsigned short u) {
    union { unsigned int i; float f; } c; c.i = ((unsigned int)u) << 16; return c.f;
}
__device__ __forceinline__ unsigned short f2bf(float f) {
    return __builtin_bit_cast(unsigned short, __float2bfloat16(f));
}
// pack 8 floats -> 8 fp8(e4m3) bytes
__device__ __forceinline__ uint2 pack_fp8x8(const float* f) {
    unsigned int lo = 0, hi = 0;
    lo = __builtin_amdgcn_cvt_pk_fp8_f32(f[0], f[1], lo, 0);
    lo = __builtin_amdgcn_cvt_pk_fp8_f32(f[2], f[3], lo, 1);
    hi = __builtin_amdgcn_cvt_pk_fp8_f32(f[4], f[5], hi, 0);
    hi = __builtin_amdgcn_cvt_pk_fp8_f32(f[6], f[7], hi, 1);
    return make_uint2(lo, hi);
}
__device__ __forceinline__ void unpack_fp8x8(uint2 v, float* f) {
    f[0] = __builtin_amdgcn_cvt_f32_fp8(v.x, 0);
    f[1] = __builtin_amdgcn_cvt_f32_fp8(v.x, 1);
    f[2] = __builtin_amdgcn_cvt_f32_fp8(v.x, 2);
    f[3] = __builtin_amdgcn_cvt_f32_fp8(v.x, 3);
    f[4] = __builtin_amdgcn_cvt_f32_fp8(v.y, 0);
    f[5] = __builtin_amdgcn_cvt_f32_fp8(v.y, 1);
    f[6] = __builtin_amdgcn_cvt_f32_fp8(v.y, 2);
    f[7] = __builtin_amdgcn_cvt_f32_fp8(v.y, 3);
}

// ---------------- front: partition (first pchunks blocks) + weight prep + projection
__global__ __launch_bounds__(256) void front_kernel(
    const int* __restrict__ src, const int* __restrict__ dst,
    int* __restrict__ rcnt, int* __restrict__ bucket, int E, int nreg, int cap, int pchunks,
    const float* __restrict__ x, const float* __restrict__ pw, const float* __restrict__ pb,
    unsigned char* __restrict__ h8, int N,
    const float* __restrict__ cw1, const float* __restrict__ cw2,
    unsigned short* __restrict__ wt, int wtotal, int wblocks) {
    int b = blockIdx.x;
    int tid = threadIdx.x;
    if (b < pchunks) {
        // ---- partition ----
        __shared__ int hcnt[256];
        __shared__ int hbase[256];
        hcnt[tid] = 0;
        __syncthreads();
        int e0 = b * PCHUNK;
        int e1 = min(e0 + PCHUNK, E);
        int nv = (e1 - e0) >> 2;
        const int4* dst4 = (const int4*)(dst + e0);
        const int4* src4 = (const int4*)(src + e0);
        for (int k = tid; k < nv; k += 256) {
            int4 d = dst4[k];
            atomicAdd(&hcnt[d.x >> 9], 1);
            atomicAdd(&hcnt[d.y >> 9], 1);
            atomicAdd(&hcnt[d.z >> 9], 1);
            atomicAdd(&hcnt[d.w >> 9], 1);
        }
        for (int e = e0 + (nv << 2) + tid; e < e1; e += 256)
            atomicAdd(&hcnt[dst[e] >> 9], 1);
        __syncthreads();
        {
            int c = hcnt[tid];
            hbase[tid] = (c > 0) ? atomicAdd(&rcnt[tid], c) : 0;
            hcnt[tid] = 0;
        }
        __syncthreads();
        for (int k = tid; k < nv; k += 256) {
            int4 d = dst4[k];
            int4 s = src4[k];
            int r, pos;
            r = d.x >> 9; pos = hbase[r] + atomicAdd(&hcnt[r], 1);
            if (pos < cap) bucket[(size_t)r * cap + pos] = ((d.x & (REGSZ - 1)) << 17) | s.x;
            r = d.y >> 9; pos = hbase[r] + atomicAdd(&hcnt[r], 1);
            if (pos < cap) bucket[(size_t)r * cap + pos] = ((d.y & (REGSZ - 1)) << 17) | s.y;
            r = d.z >> 9; pos = hbase[r] + atomicAdd(&hcnt[r], 1);
            if (pos < cap) bucket[(size_t)r * cap + pos] = ((d.z & (REGSZ - 1)) << 17) | s.z;
            r = d.w >> 9; pos = hbase[r] + atomicAdd(&hcnt[r], 1);
            if (pos < cap) bucket[(size_t)r * cap + pos] = ((d.w & (REGSZ - 1)) << 17) | s.w;
        }
        for (int e = e0 + (nv << 2) + tid; e < e1; e += 256) {
            int d = dst[e], s = src[e];
            int r = d >> 9;
            int pos = hbase[r] + atomicAdd(&hcnt[r], 1);
            if (pos < cap) bucket[(size_t)r * cap + pos] = ((d & (REGSZ - 1)) << 17) | s;
        }
        return;
    }
    b -= pchunks;
    if (b < wblocks) {
        int idx = b * 256 + tid;
        if (idx < wtotal) {
            int m = idx >> 14;
            int o = (idx >> 7) & 127;
            int i = idx & 127;
            const float* srcp = (m < 3) ? (cw1 + (size_t)m * H * H) : (cw2 + (size_t)(m - 3) * H * H);
            wt[idx] = f2bf(srcp[i * H + o]);
        }
        return;
    }
    int t2 = (b - wblocks) * 256 + tid;
    if (t2 >= N * 16) return;
    int i = t2 >> 4, c = (t2 & 15) * 8;
    float4 xv = *(const float4*)&x[i * 4];
    float acc[8];
#pragma unroll
    for (int j = 0; j < 8; ++j)
        acc[j] = pb[c + j] + xv.x * pw[0 * H + c + j] + xv.y * pw[1 * H + c + j]
               + xv.z * pw[2 * H + c + j] + xv.w * pw[3 * H + c + j];
    *(uint2*)&h8[(size_t)i * H + c] = pack_fp8x8(acc);
}

// one block per region: local histogram -> LDS scan -> place -> write offs ends.
__global__ __launch_bounds__(256) void csr_region_kernel(
    const int* __restrict__ rcnt, const int* __restrict__ bucket,
    int* __restrict__ offs, int* __restrict__ esrc,
    int N, int nreg, int cap) {
    __shared__ int cnt[REGSZ];
    __shared__ int part[256];
    __shared__ int sbase;
    int r = blockIdx.x;
    int tid = threadIdx.x;

    int v = (tid < nreg) ? rcnt[tid] : 0;
    part[tid] = v;
    __syncthreads();
    for (int off = 1; off < 256; off <<= 1) {
        int t = (tid >= off) ? part[tid - off] : 0;
        __syncthreads();
        part[tid] += t;
        __syncthreads();
    }
    if (tid == 0) sbase = (r == 0) ? 0 : part[r - 1];
    cnt[tid] = 0;
    cnt[tid + 256] = 0;
    __syncthreads();
    int base = sbase;
    int n = min(part[r] - base, cap);
    const int* bk = bucket + (size_t)r * cap;

    for (int p = tid; p < n; p += 256)
        atomicAdd(&cnt[bk[p] >> 17], 1);
    __syncthreads();

    int c0 = cnt[tid * 2], c1 = cnt[tid * 2 + 1];
    part[tid] = c0 + c1;
    __syncthreads();
    for (int off = 1; off < 256; off <<= 1) {
        int t = (tid >= off) ? part[tid - off] : 0;
        __syncthreads();
        part[tid] += t;
        __syncthreads();
    }
    int excl = (tid == 0) ? 0 : part[tid - 1];
    cnt[tid * 2] = excl;
    cnt[tid * 2 + 1] = excl + c0;
    __syncthreads();

    for (int p = tid; p < n; p += 256) {
        int e = bk[p];
        int pos = atomicAdd(&cnt[e >> 17], 1);
        esrc[base + pos] = e & 0x1FFFF;
    }
    __syncthreads();

    int lo = r * REGSZ;
#pragma unroll
    for (int i = tid; i < REGSZ; i += 256) {
        int node = lo + i;
        if (node < N) offs[node] = base + cnt[i];
    }
}

// ---------------- gather + self, 4 L2-quartered passes over src space
// pre[n][:] = h8[n][:] + sum_nbrs h8[:]  (fp8 in, fp32 acc, bf16 out)
__global__ void gather_agg_kernel(const int* __restrict__ offs, const int* __restrict__ esrc,
                                  const unsigned char* __restrict__ h8, unsigned short* __restrict__ pre, int N) {
    int tid = blockIdx.x * 256 + threadIdx.x;
    if (tid >= N * 16) return;
    int node = tid >> 4, c = (tid & 15) * 8;
    int s = (node == 0) ? 0 : offs[node - 1];
    int e = offs[node];
    float acc[8];
    unpack_fp8x8(*(const uint2*)&h8[(size_t)node * H + c], acc);   // self term
    int qsz = (N + 3) >> 2;
#pragma unroll
    for (int p = 0; p < 4; ++p) {
        int lo = p * qsz, hi = lo + qsz;
        for (int i = s; i < e; ++i) {
            int sidx = esrc[i];
            if (sidx >= lo && sidx < hi) {
                uint2 v = *(const uint2*)&h8[(size_t)sidx * H + c];
                acc[0] += __builtin_amdgcn_cvt_f32_fp8(v.x, 0);
                acc[1] += __builtin_amdgcn_cvt_f32_fp8(v.x, 1);
                acc[2] += __builtin_amdgcn_cvt_f32_fp8(v.x, 2);
                acc[3] += __builtin_amdgcn_cvt_f32_fp8(v.x, 3);
                acc[4] += __builtin_amdgcn_cvt_f32_fp8(v.y, 0);
                acc[5] += __builtin_amdgcn_cvt_f32_fp8(v.y, 1);
                acc[6] += __builtin_amdgcn_cvt_f32_fp8(v.y, 2);
                acc[7] += __builtin_amdgcn_cvt_f32_fp8(v.y, 3);
            }
        }
    }
    short8 o;
#pragma unroll
    for (int j = 0; j < 8; ++j) o[j] = (short)f2bf(acc[j]);
    *(short8*)&pre[(size_t)node * H + c] = o;
}

// ---------------- fused GIN MLP: out = relu( relu(pre@W1t^T+b1) @ W2t^T + b2 )
// BM=256 rows, 1024 threads = 16 waves (8 row-groups x 2 col-groups), wave = 32 rows x 64 cols.
// LAST=false: write fp8 h8. LAST=true: parallel segment-reduce rows by graph into gsum.
template <bool LAST>
__global__ __launch_bounds__(1024) void fused_mlp_kernel(
    const unsigned short* __restrict__ pre,
    const unsigned short* __restrict__ W1t, const unsigned short* __restrict__ W2t,
    const float* __restrict__ b1, const float* __restrict__ b2,
    unsigned char* __restrict__ h8, const int* __restrict__ batch,
    float* __restrict__ gsum, int N) {
    __shared__ unsigned short As[256 * H];   // 64KB
    __shared__ unsigned short Ws1[H * H];    // 32KB
    __shared__ unsigned short Ws2[H * H];    // 32KB
    __shared__ int sbatch[256];
    int bm = blockIdx.x * 256;
    int tid = threadIdx.x;

#pragma unroll
    for (int rep = 0; rep < 4; ++rep) {
        int lin = rep * 1024 + tid;
        int r = lin >> 4, cb = lin & 15;
        int row = bm + r;
        short8 vv = {};
        if (row < N) vv = *(const short8*)&pre[(size_t)row * H + cb * 8];
        int byte = r * 256 + ((cb * 16) ^ ((r & 7) << 4));
        *(short8*)((char*)As + byte) = vv;
    }
#pragma unroll
    for (int rep = 0; rep < 2; ++rep) {
        int lin = rep * 1024 + tid;
        int o = lin >> 4, cb = lin & 15;
        int byte = o * 256 + ((cb * 16) ^ ((o & 7) << 4));
        *(short8*)((char*)Ws1 + byte) = *(const short8*)&W1t[(size_t)o * H + cb * 8];
        *(short8*)((char*)Ws2 + byte) = *(const short8*)&W2t[(size_t)o * H + cb * 8];
    }
    if (LAST && tid < 256) {
        int row = bm + tid;
        sbatch[tid] = (row < N) ? batch[row] : -1;
    }
    __syncthreads();

    int lane = tid & 63;
    int w = tid >> 6;
    int wr = (w >> 1) * 32;
    int wc = (w & 1) * 64;
    int lrow = lane & 15, kg = lane >> 4;

    float b1v[4], b2v[4];
#pragma unroll
    for (int ct = 0; ct < 4; ++ct) {
        b1v[ct] = b1[wc + ct * 16 + lrow];
        b2v[ct] = b2[wc + ct * 16 + lrow];
    }

    short8 a[2][4];
#pragma unroll
    for (int rt = 0; rt < 2; ++rt)
#pragma unroll
        for (int ks = 0; ks < 4; ++ks) {
            int r = wr + rt * 16 + lrow;
            int kb = ks * 64 + kg * 16;
            a[rt][ks] = *(short8*)((char*)As + r * 256 + (kb ^ ((r & 7) << 4)));
        }

    f32x4 acc[2][4] = {};
#pragma unroll
    for (int ct = 0; ct < 4; ++ct) {
#pragma unroll
        for (int ks = 0; ks < 4; ++ks) {
            int o = wc + ct * 16 + lrow;
            int kb = ks * 64 + kg * 16;
            short8 b = *(short8*)((char*)Ws1 + o * 256 + (kb ^ ((o & 7) << 4)));
            acc[0][ct] = __builtin_amdgcn_mfma_f32_16x16x32_bf16(a[0][ks], b, acc[0][ct], 0, 0, 0);
            acc[1][ct] = __builtin_amdgcn_mfma_f32_16x16x32_bf16(a[1][ks], b, acc[1][ct], 0, 0, 0);
        }
    }
    __syncthreads();

#pragma unroll
    for (int rt = 0; rt < 2; ++rt)
#pragma unroll
        for (int ct = 0; ct < 4; ++ct)
#pragma unroll
            for (int rr = 0; rr < 4; ++rr) {
                int r = wr + rt * 16 + kg * 4 + rr;
                int col = wc + ct * 16 + lrow;
                float v = fmaxf(acc[rt][ct][rr] + b1v[ct], 0.f);
                int byte = r * 256 + ((col * 2) ^ ((r & 7) << 4));
                *(unsigned short*)((char*)As + byte) = f2bf(v);
            }
    __syncthreads();

#pragma unroll
    for (int rt = 0; rt < 2; ++rt)
#pragma unroll
        for (int ks = 0; ks < 4; ++ks) {
            int r = wr + rt * 16 + lrow;
            int kb = ks * 64 + kg * 16;
            a[rt][ks] = *(short8*)((char*)As + r * 256 + (kb ^ ((r & 7) << 4)));
        }

    f32x4 acc2[2][4] = {};
#pragma unroll
    for (int ct = 0; ct < 4; ++ct) {
#pragma unroll
        for (int ks = 0; ks < 4; ++ks) {
            int o = wc + ct * 16 + lrow;
            int kb = ks * 64 + kg * 16;
            short8 b = *(short8*)((char*)Ws2 + o * 256 + (kb ^ ((o & 7) << 4)));
            acc2[0][ct] = __builtin_amdgcn_mfma_f32_16x16x32_bf16(a[0][ks], b, acc2[0][ct], 0, 0, 0);
            acc2[1][ct] = __builtin_amdgcn_mfma_f32_16x16x32_bf16(a[1][ks], b, acc2[1][ct], 0, 0, 0);
        }
    }
    __syncthreads();

#pragma unroll
    for (int rt = 0; rt < 2; ++rt)
#pragma unroll
        for (int ct = 0; ct < 4; ++ct)
#pragma unroll
            for (int rr = 0; rr < 4; ++rr) {
                int r = wr + rt * 16 + kg * 4 + rr;
                int col = wc + ct * 16 + lrow;
                float v = fmaxf(acc2[rt][ct][rr] + b2v[ct], 0.f);
                As[r * H + col] = f2bf(v);
            }
    __syncthreads();

    if (!LAST) {
#pragma unroll
        for (int rep = 0; rep < 4; ++rep) {
            int lin = rep * 1024 + tid;
            int r = lin >> 4, cb = lin & 15;
            int row = bm + r;
            if (row < N) {
                short8 v = *(short8*)&As[r * H + cb * 8];
                float f[8];
#pragma unroll
                for (int j = 0; j < 8; ++j) f[j] = bf2f((unsigned short)v[j]);
                *(uint2*)&h8[(size_t)row * H + cb * 8] = pack_fp8x8(f);
            }
        }
    } else {
        int col = tid & 127;
        int rg = tid >> 7;
        int r0 = rg * 32;
        int rmax = min(r0 + 32, N - bm);
        if (r0 < rmax) {
            float accp = 0.f;
            int cur = sbatch[r0];
            for (int r = r0; r < rmax; ++r) {
                int g = sbatch[r];
                if (g != cur) {
                    atomicAdd(&gsum[(size_t)cur * H + col], accp);
                    cur = g;
                    accp = 0.f;
                }
                accp += bf2f(As[r * H + col]);
            }
            atomicAdd(&gsum[(size_t)cur * H + col], accp);
        }
    }
}

// ---------------- head: gm = gsum/cnt; t = relu(gm@sw+sb); energy/dipole
__global__ __launch_bounds__(128) void head_kernel(
    const float* __restrict__ gsum, const int* __restrict__ batch,
    const float* __restrict__ sw, const float* __restrict__ sb,
    const float* __restrict__ ew, const float* __restrict__ eb,
    const float* __restrict__ dw, const float* __restrict__ db,
    float* __restrict__ out, int N, int G) {
    int g = blockIdx.x;
    int j = threadIdx.x;
    int s, e;
    {
        int lo = 0, hi = N;
        while (lo < hi) { int mid = (lo + hi) >> 1; if (batch[mid] < g) lo = mid + 1; else hi = mid; }
        s = lo;
        hi = N;
        while (lo < hi) { int mid = (lo + hi) >> 1; if (batch[mid] < g + 1) lo = mid + 1; else hi = mid; }
        e = lo;
    }
    float cnt = (float)(e - s);
    __shared__ float gm[H];
    gm[j] = gsum[(size_t)g * H + j] / fmaxf(cnt, 1.0f);
    __syncthreads();
    float t = sb[j];
    for (int k = 0; k < H; ++k) t += gm[k] * sw[k * H + j];
    t = fmaxf(t, 0.f);
    __shared__ float red[2][H];
    red[0][j] = t * ew[j];
    red[1][j] = t * dw[j];
    __syncthreads();
    for (int off = 64; off > 0; off >>= 1) {
        if (j < off) {
            red[0][j] += red[0][j + off];
            red[1][j] += red[1][j + off];
        }
        __syncthreads();
    }
    if (j == 0) {
        out[g] = red[0][0] + eb[0];
        out[G + g] = red[1][0] + db[0];
    }
}

extern "C" void kernel_launch(void* const* d_in, const int* in_sizes, int n_in,
                              void* d_out, int out_size, void* d_ws, size_t ws_size,
                              hipStream_t stream) {
    const float* x      = (const float*)d_in[0];
    const int*   ei     = (const int*)d_in[1];
    const int*   batch  = (const int*)d_in[2];
    const float* proj_w = (const float*)d_in[3];
    const float* proj_b = (const float*)d_in[4];
    const float* cw1    = (const float*)d_in[5];
    const float* cb1    = (const float*)d_in[6];
    const float* cw2    = (const float*)d_in[7];
    const float* cb2    = (const float*)d_in[8];
    const float* sw     = (const float*)d_in[9];
    const float* sb     = (const float*)d_in[10];
    const float* ew     = (const float*)d_in[11];
    const float* eb     = (const float*)d_in[12];
    const float* dw     = (const float*)d_in[13];
    const float* db     = (const float*)d_in[14];

    int N = in_sizes[0] / 4;
    int E = in_sizes[1] / 2;
    int G = out_size / 2;

    const int* src = ei;
    const int* dst = ei + E;

    unsigned short* pre = (unsigned short*)d_ws;          // N*H bf16 (bucket overlaps)
    unsigned short* wt  = pre + (size_t)N * H;            // 6*H*H bf16
    int* offs  = (int*)(wt + 6 * H * H);                  // N+1
    int* rcnt  = offs + N + 1;                            // 256
    float* gsum = (float*)(rcnt + 256);                   // G*H fp32 (memset with rcnt)
    int* esrc  = (int*)(gsum + (size_t)G * H);            // E
    unsigned char* h8 = (unsigned char*)(esrc + E);       // N*H fp8
    int* bucket = (int*)pre;                              // nreg*cap ints (free until layer loop)

    float* out = (float*)d_out;

    int nreg = (N + REGSZ - 1) >> 9;                      // 196 for N=100000
    int cap  = (E / nreg) * 5 / 4 + 1024;

    hipMemsetAsync(rcnt, 0, (256 + (size_t)G * H) * sizeof(int), stream);

    // ---- front: partition + weight prep + projection (one dispatch) ----
    int pchunks = (E + PCHUNK - 1) / PCHUNK;
    int wtotal = 6 * H * H;
    int wblocks = (wtotal + 255) / 256;
    int pblocks = (N * 16 + 255) / 256;
    front_kernel<<<pchunks + wblocks + pblocks, 256, 0, stream>>>(
        src, dst, rcnt, bucket, E, nreg, cap, pchunks,
        x, proj_w, proj_b, h8, N, cw1, cw2, wt, wtotal, wblocks);

    csr_region_kernel<<<nreg, 256, 0, stream>>>(rcnt, bucket, offs, esrc, N, nreg, cap);

    int mlp_blocks = (N + 255) / 256;
    int gather_blocks = (N * 16 + 255) / 256;

    for (int l = 0; l < 3; ++l) {
        gather_agg_kernel<<<gather_blocks, 256, 0, stream>>>(offs, esrc, h8, pre, N);
        if (l < 2)
            fused_mlp_kernel<false><<<mlp_blocks, 1024, 0, stream>>>(
                pre, wt + (size_t)l * H * H, wt + (size_t)(3 + l) * H * H,
                cb1 + l * H, cb2 + l * H, h8, batch, gsum, N);
        else
            fused_mlp_kernel<true><<<mlp_blocks, 1024, 0, stream>>>(
                pre, wt + (size_t)l * H * H, wt + (size_t)(3 + l) * H * H,
                cb1 + l * H, cb2 + l * H, h8, batch, gsum, N);
    }

    head_kernel<<<G, 128, 0, stream>>>(gsum, batch, sw, sb, ew, eb, dw, db, out, N, G);
}

// Round 21
// 291.082 us; speedup vs baseline: 2.2464x; 2.2464x over previous
//
#include <hip/hip_runtime.h>
#include <hip/hip_bf16.h>

#define H 128
#define REGSZ 512      // nodes per region (power of 2)
#define PCHUNK 4096    // edges per partition block

typedef short short8 __attribute__((ext_vector_type(8)));
typedef float f32x4 __attribute__((ext_vector_type(4)));

__device__ __forceinline__ float bf2f(unsigned short u) {
    union { unsigned int i; float f; } c; c.i = ((unsigned int)u) << 16; return c.f;
}
__device__ __forceinline__ unsigned short f2bf(float f) {
    return __builtin_bit_cast(unsigned short, __float2bfloat16(f));
}
// pack 8 floats -> 8 fp8(e4m3) bytes
__device__ __forceinline__ uint2 pack_fp8x8(const float* f) {
    unsigned int lo = 0, hi = 0;
    lo = __builtin_amdgcn_cvt_pk_fp8_f32(f[0], f[1], lo, 0);
    lo = __builtin_amdgcn_cvt_pk_fp8_f32(f[2], f[3], lo, 1);
    hi = __builtin_amdgcn_cvt_pk_fp8_f32(f[4], f[5], hi, 0);
    hi = __builtin_amdgcn_cvt_pk_fp8_f32(f[6], f[7], hi, 1);
    return make_uint2(lo, hi);
}
__device__ __forceinline__ void unpack_fp8x8(uint2 v, float* f) {
    f[0] = __builtin_amdgcn_cvt_f32_fp8(v.x, 0);
    f[1] = __builtin_amdgcn_cvt_f32_fp8(v.x, 1);
    f[2] = __builtin_amdgcn_cvt_f32_fp8(v.x, 2);
    f[3] = __builtin_amdgcn_cvt_f32_fp8(v.x, 3);
    f[4] = __builtin_amdgcn_cvt_f32_fp8(v.y, 0);
    f[5] = __builtin_amdgcn_cvt_f32_fp8(v.y, 1);
    f[6] = __builtin_amdgcn_cvt_f32_fp8(v.y, 2);
    f[7] = __builtin_amdgcn_cvt_f32_fp8(v.y, 3);
}

// ---------------- front: partition (first pchunks blocks) + weight prep + projection
__global__ __launch_bounds__(256) void front_kernel(
    const int* __restrict__ src, const int* __restrict__ dst,
    int* __restrict__ rcnt, int* __restrict__ bucket, int E, int nreg, int cap, int pchunks,
    const float* __restrict__ x, const float* __restrict__ pw, const float* __restrict__ pb,
    unsigned char* __restrict__ h8, int N,
    const float* __restrict__ cw1, const float* __restrict__ cw2,
    unsigned short* __restrict__ wt, int wtotal, int wblocks) {
    int b = blockIdx.x;
    int tid = threadIdx.x;
    if (b < pchunks) {
        __shared__ int hcnt[256];
        __shared__ int hbase[256];
        hcnt[tid] = 0;
        __syncthreads();
        int e0 = b * PCHUNK;
        int e1 = min(e0 + PCHUNK, E);
        int nv = (e1 - e0) >> 2;
        const int4* dst4 = (const int4*)(dst + e0);
        const int4* src4 = (const int4*)(src + e0);
        for (int k = tid; k < nv; k += 256) {
            int4 d = dst4[k];
            atomicAdd(&hcnt[d.x >> 9], 1);
            atomicAdd(&hcnt[d.y >> 9], 1);
            atomicAdd(&hcnt[d.z >> 9], 1);
            atomicAdd(&hcnt[d.w >> 9], 1);
        }
        for (int e = e0 + (nv << 2) + tid; e < e1; e += 256)
            atomicAdd(&hcnt[dst[e] >> 9], 1);
        __syncthreads();
        {
            int c = hcnt[tid];
            hbase[tid] = (c > 0) ? atomicAdd(&rcnt[tid], c) : 0;
            hcnt[tid] = 0;
        }
        __syncthreads();
        for (int k = tid; k < nv; k += 256) {
            int4 d = dst4[k];
            int4 s = src4[k];
            int r, pos;
            r = d.x >> 9; pos = hbase[r] + atomicAdd(&hcnt[r], 1);
            if (pos < cap) bucket[(size_t)r * cap + pos] = ((d.x & (REGSZ - 1)) << 17) | s.x;
            r = d.y >> 9; pos = hbase[r] + atomicAdd(&hcnt[r], 1);
            if (pos < cap) bucket[(size_t)r * cap + pos] = ((d.y & (REGSZ - 1)) << 17) | s.y;
            r = d.z >> 9; pos = hbase[r] + atomicAdd(&hcnt[r], 1);
            if (pos < cap) bucket[(size_t)r * cap + pos] = ((d.z & (REGSZ - 1)) << 17) | s.z;
            r = d.w >> 9; pos = hbase[r] + atomicAdd(&hcnt[r], 1);
            if (pos < cap) bucket[(size_t)r * cap + pos] = ((d.w & (REGSZ - 1)) << 17) | s.w;
        }
        for (int e = e0 + (nv << 2) + tid; e < e1; e += 256) {
            int d = dst[e], s = src[e];
            int r = d >> 9;
            int pos = hbase[r] + atomicAdd(&hcnt[r], 1);
            if (pos < cap) bucket[(size_t)r * cap + pos] = ((d & (REGSZ - 1)) << 17) | s;
        }
        return;
    }
    b -= pchunks;
    if (b < wblocks) {
        int idx = b * 256 + tid;
        if (idx < wtotal) {
            int m = idx >> 14;
            int o = (idx >> 7) & 127;
            int i = idx & 127;
            const float* srcp = (m < 3) ? (cw1 + (size_t)m * H * H) : (cw2 + (size_t)(m - 3) * H * H);
            wt[idx] = f2bf(srcp[i * H + o]);
        }
        return;
    }
    int t2 = (b - wblocks) * 256 + tid;
    if (t2 >= N * 16) return;
    int i = t2 >> 4, c = (t2 & 15) * 8;
    float4 xv = *(const float4*)&x[i * 4];
    float acc[8];
#pragma unroll
    for (int j = 0; j < 8; ++j)
        acc[j] = pb[c + j] + xv.x * pw[0 * H + c + j] + xv.y * pw[1 * H + c + j]
               + xv.z * pw[2 * H + c + j] + xv.w * pw[3 * H + c + j];
    *(uint2*)&h8[(size_t)i * H + c] = pack_fp8x8(acc);
}

// one block per region: local histogram -> LDS scan -> place -> write offs ends.
__global__ __launch_bounds__(256) void csr_region_kernel(
    const int* __restrict__ rcnt, const int* __restrict__ bucket,
    int* __restrict__ offs, int* __restrict__ esrc,
    int N, int nreg, int cap) {
    __shared__ int cnt[REGSZ];
    __shared__ int part[256];
    __shared__ int sbase;
    int r = blockIdx.x;
    int tid = threadIdx.x;

    int v = (tid < nreg) ? rcnt[tid] : 0;
    part[tid] = v;
    __syncthreads();
    for (int off = 1; off < 256; off <<= 1) {
        int t = (tid >= off) ? part[tid - off] : 0;
        __syncthreads();
        part[tid] += t;
        __syncthreads();
    }
    if (tid == 0) sbase = (r == 0) ? 0 : part[r - 1];
    cnt[tid] = 0;
    cnt[tid + 256] = 0;
    __syncthreads();
    int base = sbase;
    int n = min(part[r] - base, cap);
    const int* bk = bucket + (size_t)r * cap;

    for (int p = tid; p < n; p += 256)
        atomicAdd(&cnt[bk[p] >> 17], 1);
    __syncthreads();

    int c0 = cnt[tid * 2], c1 = cnt[tid * 2 + 1];
    part[tid] = c0 + c1;
    __syncthreads();
    for (int off = 1; off < 256; off <<= 1) {
        int t = (tid >= off) ? part[tid - off] : 0;
        __syncthreads();
        part[tid] += t;
        __syncthreads();
    }
    int excl = (tid == 0) ? 0 : part[tid - 1];
    cnt[tid * 2] = excl;
    cnt[tid * 2 + 1] = excl + c0;
    __syncthreads();

    for (int p = tid; p < n; p += 256) {
        int e = bk[p];
        int pos = atomicAdd(&cnt[e >> 17], 1);
        esrc[base + pos] = e & 0x1FFFF;
    }
    __syncthreads();

    int lo = r * REGSZ;
#pragma unroll
    for (int i = tid; i < REGSZ; i += 256) {
        int node = lo + i;
        if (node < N) offs[node] = base + cnt[i];
    }
}

// ---------------- gather + self: pre[n][:] = h8[n][:] + sum_nbrs h8[:]  (fp8 in, fp32 acc, bf16 out)
// row-major h8, 16 lanes per node, uint2 (8 fp8) loads, 4-way ILP  [51.5us floor, R12/R18-validated]
__global__ void gather_agg_kernel(const int* __restrict__ offs, const int* __restrict__ esrc,
                                  const unsigned char* __restrict__ h8, unsigned short* __restrict__ pre, int N) {
    int tid = blockIdx.x * 256 + threadIdx.x;
    if (tid >= N * 16) return;
    int node = tid >> 4, c = (tid & 15) * 8;
    int s = (node == 0) ? 0 : offs[node - 1];
    int e = offs[node];
    float acc[8];
    unpack_fp8x8(*(const uint2*)&h8[(size_t)node * H + c], acc);   // self term
    int i = s;
    for (; i + 3 < e; i += 4) {
        uint2 v[4];
#pragma unroll
        for (int k = 0; k < 4; ++k) v[k] = *(const uint2*)&h8[(size_t)esrc[i + k] * H + c];
#pragma unroll
        for (int k = 0; k < 4; ++k) {
            acc[0] += __builtin_amdgcn_cvt_f32_fp8(v[k].x, 0);
            acc[1] += __builtin_amdgcn_cvt_f32_fp8(v[k].x, 1);
            acc[2] += __builtin_amdgcn_cvt_f32_fp8(v[k].x, 2);
            acc[3] += __builtin_amdgcn_cvt_f32_fp8(v[k].x, 3);
            acc[4] += __builtin_amdgcn_cvt_f32_fp8(v[k].y, 0);
            acc[5] += __builtin_amdgcn_cvt_f32_fp8(v[k].y, 1);
            acc[6] += __builtin_amdgcn_cvt_f32_fp8(v[k].y, 2);
            acc[7] += __builtin_amdgcn_cvt_f32_fp8(v[k].y, 3);
        }
    }
    for (; i < e; ++i) {
        uint2 v = *(const uint2*)&h8[(size_t)esrc[i] * H + c];
        acc[0] += __builtin_amdgcn_cvt_f32_fp8(v.x, 0);
        acc[1] += __builtin_amdgcn_cvt_f32_fp8(v.x, 1);
        acc[2] += __builtin_amdgcn_cvt_f32_fp8(v.x, 2);
        acc[3] += __builtin_amdgcn_cvt_f32_fp8(v.x, 3);
        acc[4] += __builtin_amdgcn_cvt_f32_fp8(v.y, 0);
        acc[5] += __builtin_amdgcn_cvt_f32_fp8(v.y, 1);
        acc[6] += __builtin_amdgcn_cvt_f32_fp8(v.y, 2);
        acc[7] += __builtin_amdgcn_cvt_f32_fp8(v.y, 3);
    }
    short8 o;
#pragma unroll
    for (int j = 0; j < 8; ++j) o[j] = (short)f2bf(acc[j]);
    *(short8*)&pre[(size_t)node * H + c] = o;
}

// ---------------- fused GIN MLP: out = relu( relu(pre@W1t^T+b1) @ W2t^T + b2 )
// BM=256 rows, 1024 threads = 16 waves (8 row-groups x 2 col-groups), wave = 32 rows x 64 cols.
// LAST=false: write fp8 h8. LAST=true: parallel segment-reduce rows by graph into gsum.
template <bool LAST>
__global__ __launch_bounds__(1024) void fused_mlp_kernel(
    const unsigned short* __restrict__ pre,
    const unsigned short* __restrict__ W1t, const unsigned short* __restrict__ W2t,
    const float* __restrict__ b1, const float* __restrict__ b2,
    unsigned char* __restrict__ h8, const int* __restrict__ batch,
    float* __restrict__ gsum, int N) {
    __shared__ unsigned short As[256 * H];   // 64KB
    __shared__ unsigned short Ws1[H * H];    // 32KB
    __shared__ unsigned short Ws2[H * H];    // 32KB
    __shared__ int sbatch[256];
    int bm = blockIdx.x * 256;
    int tid = threadIdx.x;

#pragma unroll
    for (int rep = 0; rep < 4; ++rep) {
        int lin = rep * 1024 + tid;
        int r = lin >> 4, cb = lin & 15;
        int row = bm + r;
        short8 vv = {};
        if (row < N) vv = *(const short8*)&pre[(size_t)row * H + cb * 8];
        int byte = r * 256 + ((cb * 16) ^ ((r & 7) << 4));
        *(short8*)((char*)As + byte) = vv;
    }
#pragma unroll
    for (int rep = 0; rep < 2; ++rep) {
        int lin = rep * 1024 + tid;
        int o = lin >> 4, cb = lin & 15;
        int byte = o * 256 + ((cb * 16) ^ ((o & 7) << 4));
        *(short8*)((char*)Ws1 + byte) = *(const short8*)&W1t[(size_t)o * H + cb * 8];
        *(short8*)((char*)Ws2 + byte) = *(const short8*)&W2t[(size_t)o * H + cb * 8];
    }
    if (LAST && tid < 256) {
        int row = bm + tid;
        sbatch[tid] = (row < N) ? batch[row] : -1;
    }
    __syncthreads();

    int lane = tid & 63;
    int w = tid >> 6;
    int wr = (w >> 1) * 32;
    int wc = (w & 1) * 64;
    int lrow = lane & 15, kg = lane >> 4;

    float b1v[4], b2v[4];
#pragma unroll
    for (int ct = 0; ct < 4; ++ct) {
        b1v[ct] = b1[wc + ct * 16 + lrow];
        b2v[ct] = b2[wc + ct * 16 + lrow];
    }

    short8 a[2][4];
#pragma unroll
    for (int rt = 0; rt < 2; ++rt)
#pragma unroll
        for (int ks = 0; ks < 4; ++ks) {
            int r = wr + rt * 16 + lrow;
            int kb = ks * 64 + kg * 16;
            a[rt][ks] = *(short8*)((char*)As + r * 256 + (kb ^ ((r & 7) << 4)));
        }

    f32x4 acc[2][4] = {};
#pragma unroll
    for (int ct = 0; ct < 4; ++ct) {
#pragma unroll
        for (int ks = 0; ks < 4; ++ks) {
            int o = wc + ct * 16 + lrow;
            int kb = ks * 64 + kg * 16;
            short8 b = *(short8*)((char*)Ws1 + o * 256 + (kb ^ ((o & 7) << 4)));
            acc[0][ct] = __builtin_amdgcn_mfma_f32_16x16x32_bf16(a[0][ks], b, acc[0][ct], 0, 0, 0);
            acc[1][ct] = __builtin_amdgcn_mfma_f32_16x16x32_bf16(a[1][ks], b, acc[1][ct], 0, 0, 0);
        }
    }
    __syncthreads();

#pragma unroll
    for (int rt = 0; rt < 2; ++rt)
#pragma unroll
        for (int ct = 0; ct < 4; ++ct)
#pragma unroll
            for (int rr = 0; rr < 4; ++rr) {
                int r = wr + rt * 16 + kg * 4 + rr;
                int col = wc + ct * 16 + lrow;
                float v = fmaxf(acc[rt][ct][rr] + b1v[ct], 0.f);
                int byte = r * 256 + ((col * 2) ^ ((r & 7) << 4));
                *(unsigned short*)((char*)As + byte) = f2bf(v);
            }
    __syncthreads();

#pragma unroll
    for (int rt = 0; rt < 2; ++rt)
#pragma unroll
        for (int ks = 0; ks < 4; ++ks) {
            int r = wr + rt * 16 + lrow;
            int kb = ks * 64 + kg * 16;
            a[rt][ks] = *(short8*)((char*)As + r * 256 + (kb ^ ((r & 7) << 4)));
        }

    f32x4 acc2[2][4] = {};
#pragma unroll
    for (int ct = 0; ct < 4; ++ct) {
#pragma unroll
        for (int ks = 0; ks < 4; ++ks) {
            int o = wc + ct * 16 + lrow;
            int kb = ks * 64 + kg * 16;
            short8 b = *(short8*)((char*)Ws2 + o * 256 + (kb ^ ((o & 7) << 4)));
            acc2[0][ct] = __builtin_amdgcn_mfma_f32_16x16x32_bf16(a[0][ks], b, acc2[0][ct], 0, 0, 0);
            acc2[1][ct] = __builtin_amdgcn_mfma_f32_16x16x32_bf16(a[1][ks], b, acc2[1][ct], 0, 0, 0);
        }
    }
    __syncthreads();

#pragma unroll
    for (int rt = 0; rt < 2; ++rt)
#pragma unroll
        for (int ct = 0; ct < 4; ++ct)
#pragma unroll
            for (int rr = 0; rr < 4; ++rr) {
                int r = wr + rt * 16 + kg * 4 + rr;
                int col = wc + ct * 16 + lrow;
                float v = fmaxf(acc2[rt][ct][rr] + b2v[ct], 0.f);
                As[r * H + col] = f2bf(v);
            }
    __syncthreads();

    if (!LAST) {
#pragma unroll
        for (int rep = 0; rep < 4; ++rep) {
            int lin = rep * 1024 + tid;
            int r = lin >> 4, cb = lin & 15;
            int row = bm + r;
            if (row < N) {
                short8 v = *(short8*)&As[r * H + cb * 8];
                float f[8];
#pragma unroll
                for (int j = 0; j < 8; ++j) f[j] = bf2f((unsigned short)v[j]);
                *(uint2*)&h8[(size_t)row * H + cb * 8] = pack_fp8x8(f);
            }
        }
    } else {
        int col = tid & 127;
        int rg = tid >> 7;
        int r0 = rg * 32;
        int rmax = min(r0 + 32, N - bm);
        if (r0 < rmax) {
            float accp = 0.f;
            int cur = sbatch[r0];
            for (int r = r0; r < rmax; ++r) {
                int g = sbatch[r];
                if (g != cur) {
                    atomicAdd(&gsum[(size_t)cur * H + col], accp);
                    cur = g;
                    accp = 0.f;
                }
                accp += bf2f(As[r * H + col]);
            }
            atomicAdd(&gsum[(size_t)cur * H + col], accp);
        }
    }
}

// ---------------- head: gm = gsum/cnt; t = relu(gm@sw+sb); energy/dipole
__global__ __launch_bounds__(128) void head_kernel(
    const float* __restrict__ gsum, const int* __restrict__ batch,
    const float* __restrict__ sw, const float* __restrict__ sb,
    const float* __restrict__ ew, const float* __restrict__ eb,
    const float* __restrict__ dw, const float* __restrict__ db,
    float* __restrict__ out, int N, int G) {
    int g = blockIdx.x;
    int j = threadIdx.x;
    int s, e;
    {
        int lo = 0, hi = N;
        while (lo < hi) { int mid = (lo + hi) >> 1; if (batch[mid] < g) lo = mid + 1; else hi = mid; }
        s = lo;
        hi = N;
        while (lo < hi) { int mid = (lo + hi) >> 1; if (batch[mid] < g + 1) lo = mid + 1; else hi = mid; }
        e = lo;
    }
    float cnt = (float)(e - s);
    __shared__ float gm[H];
    gm[j] = gsum[(size_t)g * H + j] / fmaxf(cnt, 1.0f);
    __syncthreads();
    float t = sb[j];
    for (int k = 0; k < H; ++k) t += gm[k] * sw[k * H + j];
    t = fmaxf(t, 0.f);
    __shared__ float red[2][H];
    red[0][j] = t * ew[j];
    red[1][j] = t * dw[j];
    __syncthreads();
    for (int off = 64; off > 0; off >>= 1) {
        if (j < off) {
            red[0][j] += red[0][j + off];
            red[1][j] += red[1][j + off];
        }
        __syncthreads();
    }
    if (j == 0) {
        out[g] = red[0][0] + eb[0];
        out[G + g] = red[1][0] + db[0];
    }
}

extern "C" void kernel_launch(void* const* d_in, const int* in_sizes, int n_in,
                              void* d_out, int out_size, void* d_ws, size_t ws_size,
                              hipStream_t stream) {
    const float* x      = (const float*)d_in[0];
    const int*   ei     = (const int*)d_in[1];
    const int*   batch  = (const int*)d_in[2];
    const float* proj_w = (const float*)d_in[3];
    const float* proj_b = (const float*)d_in[4];
    const float* cw1    = (const float*)d_in[5];
    const float* cb1    = (const float*)d_in[6];
    const float* cw2    = (const float*)d_in[7];
    const float* cb2    = (const float*)d_in[8];
    const float* sw     = (const float*)d_in[9];
    const float* sb     = (const float*)d_in[10];
    const float* ew     = (const float*)d_in[11];
    const float* eb     = (const float*)d_in[12];
    const float* dw     = (const float*)d_in[13];
    const float* db     = (const float*)d_in[14];

    int N = in_sizes[0] / 4;
    int E = in_sizes[1] / 2;
    int G = out_size / 2;

    const int* src = ei;
    const int* dst = ei + E;

    unsigned short* pre = (unsigned short*)d_ws;          // N*H bf16 (bucket overlaps)
    unsigned short* wt  = pre + (size_t)N * H;            // 6*H*H bf16
    int* offs  = (int*)(wt + 6 * H * H);                  // N+1
    int* rcnt  = offs + N + 1;                            // 256
    float* gsum = (float*)(rcnt + 256);                   // G*H fp32 (memset with rcnt)
    int* esrc  = (int*)(gsum + (size_t)G * H);            // E
    unsigned char* h8 = (unsigned char*)(esrc + E);       // N*H fp8
    int* bucket = (int*)pre;                              // nreg*cap ints (free until layer loop)

    float* out = (float*)d_out;

    int nreg = (N + REGSZ - 1) >> 9;                      // 196 for N=100000
    int cap  = (E / nreg) * 5 / 4 + 1024;

    hipMemsetAsync(rcnt, 0, (256 + (size_t)G * H) * sizeof(int), stream);

    // ---- front: partition + weight prep + projection (one dispatch) ----
    int pchunks = (E + PCHUNK - 1) / PCHUNK;
    int wtotal = 6 * H * H;
    int wblocks = (wtotal + 255) / 256;
    int pblocks = (N * 16 + 255) / 256;
    front_kernel<<<pchunks + wblocks + pblocks, 256, 0, stream>>>(
        src, dst, rcnt, bucket, E, nreg, cap, pchunks,
        x, proj_w, proj_b, h8, N, cw1, cw2, wt, wtotal, wblocks);

    csr_region_kernel<<<nreg, 256, 0, stream>>>(rcnt, bucket, offs, esrc, N, nreg, cap);

    int mlp_blocks = (N + 255) / 256;
    int gather_blocks = (N * 16 + 255) / 256;

    for (int l = 0; l < 3; ++l) {
        gather_agg_kernel<<<gather_blocks, 256, 0, stream>>>(offs, esrc, h8, pre, N);
        if (l < 2)
            fused_mlp_kernel<false><<<mlp_blocks, 1024, 0, stream>>>(
                pre, wt + (size_t)l * H * H, wt + (size_t)(3 + l) * H * H,
                cb1 + l * H, cb2 + l * H, h8, batch, gsum, N);
        else
            fused_mlp_kernel<true><<<mlp_blocks, 1024, 0, stream>>>(
                pre, wt + (size_t)l * H * H, wt + (size_t)(3 + l) * H * H,
                cb1 + l * H, cb2 + l * H, h8, batch, gsum, N);
    }

    head_kernel<<<G, 128, 0, stream>>>(gsum, batch, sw, sb, ew, eb, dw, db, out, N, G);
}